// Round 11
// baseline (187.928 us; speedup 1.0000x reference)
//
#include <hip/hip_runtime.h>

typedef __bf16 bf16x8 __attribute__((ext_vector_type(8)));
typedef short  s16x8  __attribute__((ext_vector_type(8)));
typedef float  f32x4  __attribute__((ext_vector_type(4)));
typedef float  f32x16 __attribute__((ext_vector_type(16)));

#define DEVINL __device__ __forceinline__

DEVINL unsigned short f2bf(float f) {
  unsigned int u = __builtin_bit_cast(unsigned int, f);
  u += 0x7fffu + ((u >> 16) & 1u);   // round-to-nearest-even
  return (unsigned short)(u >> 16);
}

DEVINL void async16(const void* g, void* l) {
  __builtin_amdgcn_global_load_lds(
      (const __attribute__((address_space(1))) unsigned int*)g,
      (__attribute__((address_space(3))) unsigned int*)l, 16, 0, 0);
}

// ---------------- fused prep kernel ----------------
// blocks [0,1024)    : x fp32 -> bf16 (grid-stride float4)
// blocks [1024,5120) : W1 [1024][4096] -> w1t [4096][1024] bf16
// blocks [5120,9216) : W2 [4096][1024] -> w2t [1024][4096] bf16
// blocks [9216,9232) : qconst

__global__ __launch_bounds__(256) void prep(
    const float* __restrict__ x, const float* __restrict__ W1,
    const float* __restrict__ W2, const float* __restrict__ theta,
    const float* __restrict__ wre, const float* __restrict__ wim,
    unsigned short* __restrict__ xb, unsigned short* __restrict__ w1t,
    unsigned short* __restrict__ w2t, float* __restrict__ c1) {
  __shared__ unsigned short tile[32][33];
  const int b = blockIdx.x;
  const int tid = threadIdx.x;
  if (b < 1024) {
    int i = b * 256 + tid;
#pragma unroll
    for (int k = 0; k < 8; ++k, i += 262144) {
      float4 v = ((const float4*)x)[i];
      ushort4 o;
      o.x = f2bf(v.x); o.y = f2bf(v.y); o.z = f2bf(v.z); o.w = f2bf(v.w);
      ((ushort4*)xb)[i] = o;
    }
  } else if (b < 5120) {
    int bb = b - 1024;                      // W1: R=1024, C=4096
    int bc = (bb & 127) * 32, br = (bb >> 7) * 32;
    int tx = tid & 31, ty = tid >> 5;
#pragma unroll
    for (int i = 0; i < 32; i += 8)
      tile[ty + i][tx] = f2bf(W1[(size_t)(br + ty + i) * 4096 + (bc + tx)]);
    __syncthreads();
#pragma unroll
    for (int i = 0; i < 32; i += 8)
      w1t[(size_t)(bc + ty + i) * 1024 + (br + tx)] = tile[tx][ty + i];
  } else if (b < 9216) {
    int bb = b - 5120;                      // W2: R=4096, C=1024
    int bc = (bb & 31) * 32, br = (bb >> 5) * 32;
    int tx = tid & 31, ty = tid >> 5;
#pragma unroll
    for (int i = 0; i < 32; i += 8)
      tile[ty + i][tx] = f2bf(W2[(size_t)(br + ty + i) * 1024 + (bc + tx)]);
    __syncthreads();
#pragma unroll
    for (int i = 0; i < 32; i += 8)
      w2t[(size_t)(bc + ty + i) * 4096 + (br + tx)] = tile[tx][ty + i];
  } else {
    int i = (b - 9216) * 256 + tid;         // qconst, n = 4096
    float t = theta[i];
    c1[i] = (cosf(t) * wre[i] + sinf(t) * wim[i]) * wim[i] * 0.1f;
  }
}

// ================= GEMM1: actb = relu(qt(xb @ w1t^T + b1)) =================
// 256x256 tile, BK=64, NT=16, REPS=2. 8-phase schedule + vmcnt ledger as R10.
// NEW: 32x32x16 MFMA (4061 FLOP/cy vs 3378 for 16x16x32). Per wave: 4 M-frags
// x 2 N-frags of 32x32, acc f32x16 each (128 regs, same as before).
// A-frag: lane holds A[row=frag*32+(l&31)][k=(l>>5)*8 + ks*16 ..+8] -> 16B
// swizzled ds_read, ks XORs bits 5-6 (disjoint from (l>>5)<<4 bit 4; swizzle
// (row&7)<<4 composes by XOR as before). ds_read counts/phase unchanged.
// Epilogue: C/D row=(reg&3)+8*(reg>>2)+4*(l>>5), col=l&31 (m74/m101). Routed
// through parity-1 A-region LDS scratch (free at epilogue: last tile T=15 is
// parity 1; its A-reads drained by per-phase lgkm0 before its final BAR; next
// overwrite of parity-1 A is next rep's P1 stage, after boundary BAR).
// Boundary drain: vmcnt(16) — FIFO = [12 boundary stages, 16 epilogue
// stores]; only the stages must land before the BAR.

__global__ __launch_bounds__(512, 2) void gemm1k(
    const unsigned short* __restrict__ A,    // xb  [8192][1024]
    const unsigned short* __restrict__ Bt,   // w1t [4096][1024]
    const float* __restrict__ bias,
    const float* __restrict__ theta,
    const float* __restrict__ c1,
    unsigned short* __restrict__ Cout) {     // actb [8192][4096]
  constexpr int K = 1024, N = 4096, NT = 16, REPS = 2;
  constexpr int ABYTES = 32768, AH = 16384, AL = 2;
  constexpr int BUFSZ = 65536;
  constexpr int nTilesN = 8;                 // 4096 / 512

  __shared__ __align__(16) char lds[2 * BUFSZ];

  int nwg = gridDim.x;
  int wg = blockIdx.x;
  int sw = (wg & 7) * (nwg >> 3) + (wg >> 3);
  int rowBase = (sw / nTilesN) * 256;
  int colBase = (sw % nTilesN) * 512;

  const int t = threadIdx.x;
  const int lane = t & 63;
  const int wid = t >> 6;
  const int wr = wid >> 2, wc = wid & 3;
  const int l31 = lane & 31;
  const int l5 = lane >> 5;

  const int srow = t >> 3;
  const int scolB = ((t & 7) * 16) ^ ((srow & 7) << 4);
  const unsigned short* aSrcB = A  + (size_t)(rowBase + srow) * K + (scolB >> 1);
  const unsigned short* bSrcB = Bt + (size_t)(colBase + srow) * K + (scolB >> 1);

  // swizzled ds_read bases; frag mf: +mf*4096; ks: ^(ks<<5)
  const int aRd = (wr * 128 + l31) * 128 + ((l5 << 4) ^ ((lane & 7) << 4));
  const int bRd = ABYTES + (wc * 64 + l31) * 128 + ((l5 << 4) ^ ((lane & 7) << 4));

#define STAGE_AU(S, U, P) do {                                              \
    _Pragma("unroll") for (int j = 0; j < AL; ++j)                          \
      async16(aSrcB + ((size_t)((U) * 128 + j * 64) * K + (size_t)(S) * 64),\
              &lds[(P) * BUFSZ + (U) * AH + j * 8192 + t * 16]);            \
  } while (0)
#define STAGE_BU(SRC, S, U, P) do {                                         \
    _Pragma("unroll") for (int j = 0; j < 2; ++j)                           \
      async16((SRC) + ((size_t)((U) * 128 + j * 64) * K + (size_t)(S) * 64),\
              &lds[(P) * BUFSZ + ABYTES + (U) * 16384 + j * 8192 + t * 16]);\
  } while (0)
#define LOAD_A(H, P)                                                        \
  _Pragma("unroll") for (int m2 = 0; m2 < 2; ++m2)                          \
  _Pragma("unroll") for (int ks = 0; ks < 4; ++ks)                          \
    a[m2][ks] = __builtin_bit_cast(bf16x8, *(const s16x8*)&lds[             \
        (P) * BUFSZ + ((aRd + ((H) * 2 + m2) * 4096) ^ (ks << 5))])
#define LOAD_B(NF, P)                                                       \
  _Pragma("unroll") for (int ks = 0; ks < 4; ++ks)                          \
    b[NF][ks] = __builtin_bit_cast(bf16x8, *(const s16x8*)&lds[             \
        (P) * BUFSZ + ((bRd + (NF) * 4096) ^ (ks << 5))])
#define QUAD(H, NF)                                                         \
  __builtin_amdgcn_s_setprio(1);                                            \
  _Pragma("unroll") for (int ks = 0; ks < 4; ++ks)                          \
  _Pragma("unroll") for (int m2 = 0; m2 < 2; ++m2)                          \
    acc[(H) * 2 + m2][NF] = __builtin_amdgcn_mfma_f32_32x32x16_bf16(        \
        a[m2][ks], b[NF][ks], acc[(H) * 2 + m2][NF], 0, 0, 0);              \
  __builtin_amdgcn_s_setprio(0)
#define BAR() __builtin_amdgcn_s_barrier()
#define LG0() asm volatile("s_waitcnt lgkmcnt(0)" ::: "memory")
#define TILE(T, P) do {                                                     \
    LOAD_A(0, P); LOAD_B(0, P);                                             \
    if ((T) + 1 < NT) STAGE_AU((T) + 1, 0, (P) ^ 1);                        \
    asm volatile("s_waitcnt lgkmcnt(8)" ::: "memory");                      \
    BAR(); LG0(); QUAD(0, 0); BAR();                                        \
    LOAD_B(1, P);                                                           \
    if ((T) + 1 < NT) STAGE_AU((T) + 1, 1, (P) ^ 1);                        \
    BAR(); LG0(); QUAD(0, 1); BAR();                                        \
    LOAD_A(1, P);                                                           \
    if ((T) + 2 < NT) STAGE_BU(bSrcR, (T) + 2, 0, P);                       \
    BAR(); LG0(); QUAD(1, 1); BAR();                                        \
    if ((T) + 2 < NT) STAGE_BU(bSrcR, (T) + 2, 1, P);                       \
    BAR(); QUAD(1, 0);                                                      \
    if ((T) + 2 < NT) {                                                     \
      asm volatile("s_waitcnt vmcnt(4)" ::: "memory");                      \
    } else if ((T) + 1 < NT) {                                              \
      asm volatile("s_waitcnt vmcnt(0)" ::: "memory");                      \
    }                                                                       \
    BAR();                                                                  \
  } while (0)

  STAGE_AU(0, 0, 0); STAGE_AU(0, 1, 0);
  STAGE_BU(bSrcB, 0, 0, 0); STAGE_BU(bSrcB, 0, 1, 0);
  STAGE_BU(bSrcB, 1, 0, 1); STAGE_BU(bSrcB, 1, 1, 1);
  asm volatile("s_waitcnt vmcnt(4)" ::: "memory");
  BAR();

  for (int rep = 0; rep < REPS; ++rep) {
    const unsigned short* bSrcR = bSrcB + (size_t)rep * 256 * K;
    f32x16 acc[4][2] = {};
    bf16x8 a[2][4], b[2][4];

    for (int T = 0; T < NT; T += 2) {
      TILE(T, 0);
      TILE(T + 1, 1);
    }

    if (rep + 1 < REPS) {
      const unsigned short* bSrcN = bSrcB + (size_t)(rep + 1) * 256 * K;
      STAGE_AU(0, 0, 0); STAGE_AU(0, 1, 0);
      STAGE_BU(bSrcN, 0, 0, 0); STAGE_BU(bSrcN, 0, 1, 0);
      STAGE_BU(bSrcN, 1, 0, 1); STAGE_BU(bSrcN, 1, 1, 1);
    }

    // ---- fused epilogue (bias+quantum+relu), 32x32 frags, full-line bf16 ----
    const int colR = colBase + rep * 256;
    float bvv[2], thv[2], ccv[2];
#pragma unroll
    for (int nf = 0; nf < 2; ++nf) {
      int n = colR + wc * 64 + nf * 32 + l31;
      bvv[nf] = bias[n]; thv[nf] = theta[n]; ccv[nf] = c1[n];
    }
    const int SB = BUFSZ + wid * 4096;       // parity-1 A region as scratch
    const int rr0 = lane >> 3;               // 0..7
    const int bo = (lane & 7) * 16;
#pragma unroll
    for (int mi = 0; mi < 4; ++mi) {
#pragma unroll
      for (int nf = 0; nf < 2; ++nf) {
#pragma unroll
        for (int j = 0; j < 16; ++j) {
          int row = 8 * (j >> 2) + (j & 3) + 4 * l5;
          float h = acc[mi][nf][j] + bvv[nf];
          float q = h + ccv[nf] * __sinf(thv[nf] + 0.1f * h);
          unsigned short v = f2bf(fmaxf(q, 0.f));
          int ad = SB + row * 128 + ((nf * 64 + l31 * 2) ^ ((row & 7) << 4));
          *(unsigned short*)&lds[ad] = v;
        }
      }
      LG0();
#pragma unroll
      for (int p = 0; p < 4; ++p) {
        int rr = p * 8 + rr0;
        s16x8 w = *(const s16x8*)&lds[SB + rr * 128 + (bo ^ ((rr & 7) << 4))];
        unsigned short* dst = Cout +
            (size_t)(rowBase + wr * 128 + mi * 32 + rr) * N +
            colR + wc * 64 + (lane & 7) * 8;
        *(s16x8*)dst = w;
      }
      LG0();
    }

    if (rep + 1 < REPS) {
      asm volatile("s_waitcnt vmcnt(16)" ::: "memory");  // stages only
      BAR();
    }
  }
#undef TILE
#undef QUAD
#undef LOAD_A
#undef LOAD_B
#undef STAGE_AU
#undef STAGE_BU
#undef BAR
#undef LG0
}

// ================= GEMM2: out = actb @ w2t^T + b2 (fp32) =================
// 128x256 tile, BK=64, NT=64. 32x32x16 MFMA: 2 M-frags x 2 N-frags per wave.
// Dedicated 32KB epilogue scratch (4KB/wave, per (mi,nf) pass).

__global__ __launch_bounds__(512, 2) void gemm2k(
    const unsigned short* __restrict__ A,    // actb [8192][4096]
    const unsigned short* __restrict__ Bt,   // w2t  [1024][4096]
    const float* __restrict__ bias,
    float* __restrict__ Cout) {              // out [8192][1024]
  constexpr int K = 4096, N = 1024, NT = 64;
  constexpr int ABYTES = 16384, AH = 8192, AL = 1;
  constexpr int BUFSZ = 49152;
  constexpr int nTilesN = 4;

  __shared__ __align__(16) char lds[2 * BUFSZ + 32768];

  int nwg = gridDim.x;
  int wg = blockIdx.x;
  int sw = (wg & 7) * (nwg >> 3) + (wg >> 3);
  int rowBase = (sw / nTilesN) * 128;
  int colBase = (sw % nTilesN) * 256;

  const int t = threadIdx.x;
  const int lane = t & 63;
  const int wid = t >> 6;
  const int wr = wid >> 2, wc = wid & 3;
  const int l31 = lane & 31;
  const int l5 = lane >> 5;

  const int srow = t >> 3;
  const int scolB = ((t & 7) * 16) ^ ((srow & 7) << 4);
  const unsigned short* aSrcB = A  + (size_t)(rowBase + srow) * K + (scolB >> 1);
  const unsigned short* bSrcB = Bt + (size_t)(colBase + srow) * K + (scolB >> 1);

  const int aRd = (wr * 64 + l31) * 128 + ((l5 << 4) ^ ((lane & 7) << 4));
  const int bRd = ABYTES + (wc * 64 + l31) * 128 + ((l5 << 4) ^ ((lane & 7) << 4));

  f32x16 acc[2][2] = {};
  bf16x8 a[4], b[2][4];

#define STAGE_AU(S, U, P)                                                   \
  async16(aSrcB + ((size_t)((U) * 64) * K + (size_t)(S) * 64),              \
          &lds[(P) * BUFSZ + (U) * AH + t * 16])
#define STAGE_BU(S, U, P) do {                                              \
    _Pragma("unroll") for (int j = 0; j < 2; ++j)                           \
      async16(bSrcB + ((size_t)((U) * 128 + j * 64) * K + (size_t)(S) * 64),\
              &lds[(P) * BUFSZ + ABYTES + (U) * 16384 + j * 8192 + t * 16]);\
  } while (0)
#define LOAD_A(H, P)                                                        \
  _Pragma("unroll") for (int ks = 0; ks < 4; ++ks)                          \
    a[ks] = __builtin_bit_cast(bf16x8, *(const s16x8*)&lds[                 \
        (P) * BUFSZ + ((aRd + (H) * 4096) ^ (ks << 5))])
#define LOAD_B(NF, P)                                                       \
  _Pragma("unroll") for (int ks = 0; ks < 4; ++ks)                          \
    b[NF][ks] = __builtin_bit_cast(bf16x8, *(const s16x8*)&lds[             \
        (P) * BUFSZ + ((bRd + (NF) * 4096) ^ (ks << 5))])
#define QUAD(H, NF)                                                         \
  __builtin_amdgcn_s_setprio(1);                                            \
  _Pragma("unroll") for (int ks = 0; ks < 4; ++ks)                          \
    acc[H][NF] = __builtin_amdgcn_mfma_f32_32x32x16_bf16(                   \
        a[ks], b[NF][ks], acc[H][NF], 0, 0, 0);                             \
  __builtin_amdgcn_s_setprio(0)
#define BAR() __builtin_amdgcn_s_barrier()
#define LG0() asm volatile("s_waitcnt lgkmcnt(0)" ::: "memory")
#define TILE(T, P) do {                                                     \
    LOAD_A(0, P); LOAD_B(0, P);                                             \
    if ((T) + 1 < NT) STAGE_AU((T) + 1, 0, (P) ^ 1);                        \
    BAR(); LG0(); QUAD(0, 0); BAR();                                        \
    LOAD_B(1, P);                                                           \
    if ((T) + 1 < NT) STAGE_AU((T) + 1, 1, (P) ^ 1);                        \
    BAR(); LG0(); QUAD(0, 1); BAR();                                        \
    LOAD_A(1, P);                                                           \
    if ((T) + 2 < NT) STAGE_BU((T) + 2, 0, P);                              \
    BAR(); LG0(); QUAD(1, 1); BAR();                                        \
    if ((T) + 2 < NT) STAGE_BU((T) + 2, 1, P);                              \
    BAR(); QUAD(1, 0);                                                      \
    if ((T) + 2 < NT) {                                                     \
      asm volatile("s_waitcnt vmcnt(4)" ::: "memory");                      \
    } else if ((T) + 1 < NT) {                                              \
      asm volatile("s_waitcnt vmcnt(0)" ::: "memory");                      \
    }                                                                       \
    BAR();                                                                  \
  } while (0)

  STAGE_AU(0, 0, 0); STAGE_AU(0, 1, 0);
  STAGE_BU(0, 0, 0); STAGE_BU(0, 1, 0);
  STAGE_BU(1, 0, 1); STAGE_BU(1, 1, 1);
  asm volatile("s_waitcnt vmcnt(4)" ::: "memory");
  BAR();

  for (int T = 0; T < NT; T += 2) {
    TILE(T, 0);
    TILE(T + 1, 1);
  }
#undef TILE
#undef QUAD
#undef LOAD_A
#undef LOAD_B
#undef STAGE_AU
#undef STAGE_BU
#undef BAR

  // ---- fp32 epilogue via dedicated scratch, 32x32 frags, full-line ----
  float bvv[2];
#pragma unroll
  for (int nf = 0; nf < 2; ++nf)
    bvv[nf] = bias[colBase + wc * 64 + nf * 32 + l31];
  const int SB = 2 * BUFSZ + wid * 4096;
  const int rr0 = lane >> 3;
  const int bo = (lane & 7) * 16;
#pragma unroll
  for (int mi = 0; mi < 2; ++mi) {
#pragma unroll
    for (int nf = 0; nf < 2; ++nf) {
#pragma unroll
      for (int j = 0; j < 16; ++j) {
        int row = 8 * (j >> 2) + (j & 3) + 4 * l5;
        int ad = SB + row * 128 + ((l31 * 4) ^ ((row & 7) << 4));
        *(float*)&lds[ad] = acc[mi][nf][j] + bvv[nf];
      }
      asm volatile("s_waitcnt lgkmcnt(0)" ::: "memory");
#pragma unroll
      for (int p = 0; p < 4; ++p) {
        int rr = p * 8 + rr0;
        f32x4 v = *(const f32x4*)&lds[SB + rr * 128 +
                                      (bo ^ ((rr & 7) << 4))];
        float* dst = Cout + (size_t)(rowBase + wr * 64 + mi * 32 + rr) * N +
                     colBase + wc * 64 + nf * 32 + (lane & 7) * 4;
        *(f32x4*)dst = v;
      }
      asm volatile("s_waitcnt lgkmcnt(0)" ::: "memory");
    }
  }
}

// ---------------- launch ----------------

extern "C" void kernel_launch(void* const* d_in, const int* in_sizes, int n_in,
                              void* d_out, int out_size, void* d_ws,
                              size_t ws_size, hipStream_t stream) {
  const float* x     = (const float*)d_in[0];
  const float* W1    = (const float*)d_in[1];
  const float* b1    = (const float*)d_in[2];
  const float* theta = (const float*)d_in[3];
  const float* qwr   = (const float*)d_in[4];
  const float* qwi   = (const float*)d_in[5];
  const float* W2    = (const float*)d_in[6];
  const float* b2    = (const float*)d_in[7];
  float* out = (float*)d_out;

  const int DF = 4096;
  size_t need = ((size_t)96 << 20) + DF * sizeof(float);
  if (ws_size < need) return;

  char* ws = (char*)d_ws;
  unsigned short* xb   = (unsigned short*)ws;                          // 16 MiB
  unsigned short* w1t  = (unsigned short*)(ws + ((size_t)16 << 20));   //  8 MiB
  unsigned short* w2t  = (unsigned short*)(ws + ((size_t)24 << 20));   //  8 MiB
  unsigned short* actb = (unsigned short*)(ws + ((size_t)32 << 20));   // 64 MiB
  float* c1 = (float*)(ws + ((size_t)96 << 20));

  prep<<<9232, 256, 0, stream>>>(x, W1, W2, theta, qwr, qwi,
                                 xb, w1t, w2t, c1);
  gemm1k<<<256, 512, 0, stream>>>(xb, w1t, b1, theta, c1, actb);
  gemm2k<<<256, 512, 0, stream>>>(actb, w2t, b2, out);
}

// Round 12
// 154.683 us; speedup vs baseline: 1.2149x; 1.2149x over previous
//
#include <hip/hip_runtime.h>

typedef __bf16 bf16x8 __attribute__((ext_vector_type(8)));
typedef short  s16x8  __attribute__((ext_vector_type(8)));
typedef float  f32x4  __attribute__((ext_vector_type(4)));

#define DEVINL __device__ __forceinline__

DEVINL unsigned short f2bf(float f) {
  unsigned int u = __builtin_bit_cast(unsigned int, f);
  u += 0x7fffu + ((u >> 16) & 1u);   // round-to-nearest-even
  return (unsigned short)(u >> 16);
}

DEVINL void async16(const void* g, void* l) {
  __builtin_amdgcn_global_load_lds(
      (const __attribute__((address_space(1))) unsigned int*)g,
      (__attribute__((address_space(3))) unsigned int*)l, 16, 0, 0);
}

// ---------------- fused prep kernel ----------------
// blocks [0,1024)    : x fp32 -> bf16 (grid-stride float4)
// blocks [1024,5120) : W1 [1024][4096] -> w1t [4096][1024] bf16
// blocks [5120,9216) : W2 [4096][1024] -> w2t [1024][4096] bf16
// blocks [9216,9232) : qconst

__global__ __launch_bounds__(256) void prep(
    const float* __restrict__ x, const float* __restrict__ W1,
    const float* __restrict__ W2, const float* __restrict__ theta,
    const float* __restrict__ wre, const float* __restrict__ wim,
    unsigned short* __restrict__ xb, unsigned short* __restrict__ w1t,
    unsigned short* __restrict__ w2t, float* __restrict__ c1) {
  __shared__ unsigned short tile[32][33];
  const int b = blockIdx.x;
  const int tid = threadIdx.x;
  if (b < 1024) {
    int i = b * 256 + tid;
#pragma unroll
    for (int k = 0; k < 8; ++k, i += 262144) {
      float4 v = ((const float4*)x)[i];
      ushort4 o;
      o.x = f2bf(v.x); o.y = f2bf(v.y); o.z = f2bf(v.z); o.w = f2bf(v.w);
      ((ushort4*)xb)[i] = o;
    }
  } else if (b < 5120) {
    int bb = b - 1024;                      // W1: R=1024, C=4096
    int bc = (bb & 127) * 32, br = (bb >> 7) * 32;
    int tx = tid & 31, ty = tid >> 5;
#pragma unroll
    for (int i = 0; i < 32; i += 8)
      tile[ty + i][tx] = f2bf(W1[(size_t)(br + ty + i) * 4096 + (bc + tx)]);
    __syncthreads();
#pragma unroll
    for (int i = 0; i < 32; i += 8)
      w1t[(size_t)(bc + ty + i) * 1024 + (br + tx)] = tile[tx][ty + i];
  } else if (b < 9216) {
    int bb = b - 5120;                      // W2: R=4096, C=1024
    int bc = (bb & 31) * 32, br = (bb >> 5) * 32;
    int tx = tid & 31, ty = tid >> 5;
#pragma unroll
    for (int i = 0; i < 32; i += 8)
      tile[ty + i][tx] = f2bf(W2[(size_t)(br + ty + i) * 1024 + (bc + tx)]);
    __syncthreads();
#pragma unroll
    for (int i = 0; i < 32; i += 8)
      w2t[(size_t)(bc + ty + i) * 4096 + (br + tx)] = tile[tx][ty + i];
  } else {
    int i = (b - 9216) * 256 + tid;         // qconst, n = 4096
    float t = theta[i];
    c1[i] = (cosf(t) * wre[i] + sinf(t) * wim[i]) * wim[i] * 0.1f;
  }
}

// ================= GEMM1: actb = relu(qt(xb @ w1t^T + b1)) =================
// 256x256 tile, BK=64, NT=16, REPS=2. 8-phase schedule, 16x16x32 MFMA
// (R10-verified: 0 bank conflicts, 79 us). launch_bounds min-waves=1:
// occupancy is LDS-capped at 1 block/CU (144K/160K), so the 128-VGPR cap
// from min-waves=2 bought nothing; 256-VGPR budget frees the scheduler.

__global__ __launch_bounds__(512, 1) void gemm1k(
    const unsigned short* __restrict__ A,    // xb  [8192][1024]
    const unsigned short* __restrict__ Bt,   // w1t [4096][1024]
    const float* __restrict__ bias,
    const float* __restrict__ theta,
    const float* __restrict__ c1,
    unsigned short* __restrict__ Cout) {     // actb [8192][4096]
  constexpr int K = 1024, N = 4096, NT = 16, REPS = 2;
  constexpr int WROWS = 128, M_REP = 8, MH = 4;
  constexpr int ABYTES = 32768, AH = 16384, AL = 2;
  constexpr int BUFSZ = 65536;
  constexpr int nTilesN = 8;                 // 4096 / 512

  __shared__ __align__(16) char lds[2 * BUFSZ + 16384];

  int nwg = gridDim.x;
  int wg = blockIdx.x;
  int sw = (wg & 7) * (nwg >> 3) + (wg >> 3);
  int rowBase = (sw / nTilesN) * 256;
  int colBase = (sw % nTilesN) * 512;

  const int t = threadIdx.x;
  const int lane = t & 63;
  const int wid = t >> 6;
  const int wr = wid >> 2, wc = wid & 3;
  const int lr = lane & 15;
  const int lg = lane >> 4;
  const int r7 = lane & 7;

  const int srow = t >> 3;
  const int scolB = ((t & 7) * 16) ^ ((srow & 7) << 4);
  const unsigned short* aSrcB = A  + (size_t)(rowBase + srow) * K + (scolB >> 1);
  const unsigned short* bSrcB = Bt + (size_t)(colBase + srow) * K + (scolB >> 1);

  const int aRd = (wr * WROWS + lr) * 128 + ((lg ^ r7) << 4);
  const int bRd = ABYTES + (wc * 64 + lr) * 128 + ((lg ^ r7) << 4);

#define STAGE_AU(S, U, P) do {                                              \
    _Pragma("unroll") for (int j = 0; j < AL; ++j)                          \
      async16(aSrcB + ((size_t)((U) * WROWS + j * 64) * K + (size_t)(S) * 64),\
              &lds[(P) * BUFSZ + (U) * AH + j * 8192 + t * 16]);            \
  } while (0)
#define STAGE_BU(SRC, S, U, P) do {                                         \
    _Pragma("unroll") for (int j = 0; j < 2; ++j)                           \
      async16((SRC) + ((size_t)((U) * 128 + j * 64) * K + (size_t)(S) * 64),\
              &lds[(P) * BUFSZ + ABYTES + (U) * 16384 + j * 8192 + t * 16]);\
  } while (0)
#define LOAD_A(MHh, P)                                                      \
  _Pragma("unroll") for (int mi = 0; mi < MH; ++mi)                         \
  _Pragma("unroll") for (int ks = 0; ks < 2; ++ks)                          \
    a[mi][ks] = __builtin_bit_cast(bf16x8, *(const s16x8*)&lds[             \
        (P) * BUFSZ + ((aRd + ((MHh) * MH + mi) * 2048) ^ (ks << 6))])
#define LOAD_B(NHh, P)                                                      \
  _Pragma("unroll") for (int nn = 0; nn < 2; ++nn)                          \
  _Pragma("unroll") for (int ks = 0; ks < 2; ++ks)                          \
    b[(NHh) * 2 + nn][ks] = __builtin_bit_cast(bf16x8, *(const s16x8*)&lds[ \
        (P) * BUFSZ + ((bRd + ((NHh) * 2 + nn) * 2048) ^ (ks << 6))])
#define QUAD(MHh, NHh)                                                      \
  __builtin_amdgcn_s_setprio(1);                                            \
  _Pragma("unroll") for (int mi = 0; mi < MH; ++mi)                         \
  _Pragma("unroll") for (int nn = 0; nn < 2; ++nn)                          \
  _Pragma("unroll") for (int ks = 0; ks < 2; ++ks)                          \
    acc[(MHh) * MH + mi][(NHh) * 2 + nn] =                                  \
        __builtin_amdgcn_mfma_f32_16x16x32_bf16(                            \
            a[mi][ks], b[(NHh) * 2 + nn][ks],                               \
            acc[(MHh) * MH + mi][(NHh) * 2 + nn], 0, 0, 0);                 \
  __builtin_amdgcn_s_setprio(0)
#define BAR() __builtin_amdgcn_s_barrier()
#define LG0() asm volatile("s_waitcnt lgkmcnt(0)" ::: "memory")
#define TILE(T, P) do {                                                     \
    LOAD_A(0, P); LOAD_B(0, P);                                             \
    if ((T) + 1 < NT) STAGE_AU((T) + 1, 0, (P) ^ 1);                        \
    asm volatile("s_waitcnt lgkmcnt(8)" ::: "memory");                      \
    BAR(); LG0(); QUAD(0, 0); BAR();                                        \
    LOAD_B(1, P);                                                           \
    if ((T) + 1 < NT) STAGE_AU((T) + 1, 1, (P) ^ 1);                        \
    BAR(); LG0(); QUAD(0, 1); BAR();                                        \
    LOAD_A(1, P);                                                           \
    if ((T) + 2 < NT) STAGE_BU(bSrcR, (T) + 2, 0, P);                       \
    BAR(); LG0(); QUAD(1, 1); BAR();                                        \
    if ((T) + 2 < NT) STAGE_BU(bSrcR, (T) + 2, 1, P);                       \
    BAR(); QUAD(1, 0);                                                      \
    if ((T) + 2 < NT) {                                                     \
      asm volatile("s_waitcnt vmcnt(4)" ::: "memory");                      \
    } else if ((T) + 1 < NT) {                                              \
      asm volatile("s_waitcnt vmcnt(0)" ::: "memory");                      \
    }                                                                       \
    BAR();                                                                  \
  } while (0)

  STAGE_AU(0, 0, 0); STAGE_AU(0, 1, 0);
  STAGE_BU(bSrcB, 0, 0, 0); STAGE_BU(bSrcB, 0, 1, 0);
  STAGE_BU(bSrcB, 1, 0, 1); STAGE_BU(bSrcB, 1, 1, 1);
  asm volatile("s_waitcnt vmcnt(4)" ::: "memory");
  BAR();

  for (int rep = 0; rep < REPS; ++rep) {
    const unsigned short* bSrcR = bSrcB + (size_t)rep * 256 * K;
    f32x4 acc[M_REP][4] = {};
    bf16x8 a[MH][2], b[4][2];

    for (int T = 0; T < NT; T += 2) {
      TILE(T, 0);
      TILE(T + 1, 1);
    }

    if (rep + 1 < REPS) {
      const unsigned short* bSrcN = bSrcB + (size_t)(rep + 1) * 256 * K;
      STAGE_AU(0, 0, 0); STAGE_AU(0, 1, 0);
      STAGE_BU(bSrcN, 0, 0, 0); STAGE_BU(bSrcN, 0, 1, 0);
      STAGE_BU(bSrcN, 1, 0, 1); STAGE_BU(bSrcN, 1, 1, 1);
    }

    // ---- fused epilogue (bias + quantum + relu), full-line bf16 stores ----
    const int colR = colBase + rep * 256;
    const int ocol0 = colR + wc * 64 + lr;
    float bvv[4], thv[4], ccv[4];
#pragma unroll
    for (int ni = 0; ni < 4; ++ni) {
      int n = ocol0 + ni * 16;
      bvv[ni] = bias[n]; thv[ni] = theta[n]; ccv[ni] = c1[n];
    }
    const int SB = 2 * BUFSZ + wid * 2048;
    const size_t growB = (size_t)(rowBase + wr * WROWS) * N;
    const int rd = lane >> 3;                // 0..7
    const int bo = (lane & 7) * 16;          // 0..112
#pragma unroll
    for (int mi = 0; mi < M_REP; ++mi) {
#pragma unroll
      for (int ni = 0; ni < 4; ++ni) {
#pragma unroll
        for (int r = 0; r < 4; ++r) {
          int row16 = lg * 4 + r;
          float h = acc[mi][ni][r] + bvv[ni];
          float q = h + ccv[ni] * __sinf(thv[ni] + 0.1f * h);
          unsigned short v = f2bf(fmaxf(q, 0.f));
          int ad = SB + row16 * 128 +
                   (((ni * 16 + lr) * 2) ^ ((row16 & 7) << 4));
          *(unsigned short*)&lds[ad] = v;
        }
      }
      s16x8 w0 = *(const s16x8*)&lds[SB + rd * 128 + (bo ^ ((rd & 7) << 4))];
      s16x8 w1 = *(const s16x8*)&lds[SB + (rd + 8) * 128 +
                                     (bo ^ ((rd & 7) << 4))];
      unsigned short* dst = Cout + growB + (size_t)(mi * 16 + rd) * N +
                            colR + wc * 64 + (lane & 7) * 8;
      *(s16x8*)dst = w0;
      *(s16x8*)(dst + (size_t)8 * N) = w1;   // rows rd and rd+8
    }

    if (rep + 1 < REPS) {
      asm volatile("s_waitcnt vmcnt(0)" ::: "memory");
      BAR();
    }
  }
#undef TILE
#undef QUAD
#undef LOAD_A
#undef LOAD_B
#undef STAGE_AU
#undef STAGE_BU
#undef BAR
#undef LG0
}

// ================= GEMM2: out = actb @ w2t^T + b2 (fp32) =================
// 128x256 tile, BK=64, NT=64 — R10 structure verbatim; min-waves=1
// (LDS-capped at 1 block/CU, 128K/160K).

__global__ __launch_bounds__(512, 1) void gemm2k(
    const unsigned short* __restrict__ A,    // actb [8192][4096]
    const unsigned short* __restrict__ Bt,   // w2t  [1024][4096]
    const float* __restrict__ bias,
    float* __restrict__ Cout) {              // out [8192][1024]
  constexpr int K = 4096, N = 1024, NT = 64;
  constexpr int WROWS = 64, M_REP = 4, MH = 2;
  constexpr int ABYTES = 16384, AH = 8192, AL = 1;
  constexpr int BUFSZ = 49152;
  constexpr int nTilesN = 4;

  __shared__ __align__(16) char lds[2 * BUFSZ + 32768];

  int nwg = gridDim.x;
  int wg = blockIdx.x;
  int sw = (wg & 7) * (nwg >> 3) + (wg >> 3);
  int rowBase = (sw / nTilesN) * 128;
  int colBase = (sw % nTilesN) * 256;

  const int t = threadIdx.x;
  const int lane = t & 63;
  const int wid = t >> 6;
  const int wr = wid >> 2, wc = wid & 3;
  const int lr = lane & 15;
  const int lg = lane >> 4;
  const int r7 = lane & 7;

  const int srow = t >> 3;
  const int scolB = ((t & 7) * 16) ^ ((srow & 7) << 4);
  const unsigned short* aSrcB = A  + (size_t)(rowBase + srow) * K + (scolB >> 1);
  const unsigned short* bSrcB = Bt + (size_t)(colBase + srow) * K + (scolB >> 1);

  const int aRd = (wr * WROWS + lr) * 128 + ((lg ^ r7) << 4);
  const int bRd = ABYTES + (wc * 64 + lr) * 128 + ((lg ^ r7) << 4);

  f32x4 acc[M_REP][4] = {};
  bf16x8 a[MH][2], b[4][2];

#define STAGE_AU(S, U, P)                                                   \
  async16(aSrcB + ((size_t)((U) * 64) * K + (size_t)(S) * 64),              \
          &lds[(P) * BUFSZ + (U) * AH + t * 16])
#define STAGE_BU(S, U, P) do {                                              \
    _Pragma("unroll") for (int j = 0; j < 2; ++j)                           \
      async16(bSrcB + ((size_t)((U) * 128 + j * 64) * K + (size_t)(S) * 64),\
              &lds[(P) * BUFSZ + ABYTES + (U) * 16384 + j * 8192 + t * 16]);\
  } while (0)
#define LOAD_A(MHh, P)                                                      \
  _Pragma("unroll") for (int mi = 0; mi < MH; ++mi)                         \
  _Pragma("unroll") for (int ks = 0; ks < 2; ++ks)                          \
    a[mi][ks] = __builtin_bit_cast(bf16x8, *(const s16x8*)&lds[             \
        (P) * BUFSZ + ((aRd + ((MHh) * MH + mi) * 2048) ^ (ks << 6))])
#define LOAD_B(NHh, P)                                                      \
  _Pragma("unroll") for (int nn = 0; nn < 2; ++nn)                          \
  _Pragma("unroll") for (int ks = 0; ks < 2; ++ks)                          \
    b[(NHh) * 2 + nn][ks] = __builtin_bit_cast(bf16x8, *(const s16x8*)&lds[ \
        (P) * BUFSZ + ((bRd + ((NHh) * 2 + nn) * 2048) ^ (ks << 6))])
#define QUAD(MHh, NHh)                                                      \
  __builtin_amdgcn_s_setprio(1);                                            \
  _Pragma("unroll") for (int mi = 0; mi < MH; ++mi)                         \
  _Pragma("unroll") for (int nn = 0; nn < 2; ++nn)                          \
  _Pragma("unroll") for (int ks = 0; ks < 2; ++ks)                          \
    acc[(MHh) * MH + mi][(NHh) * 2 + nn] =                                  \
        __builtin_amdgcn_mfma_f32_16x16x32_bf16(                            \
            a[mi][ks], b[(NHh) * 2 + nn][ks],                               \
            acc[(MHh) * MH + mi][(NHh) * 2 + nn], 0, 0, 0);                 \
  __builtin_amdgcn_s_setprio(0)
#define BAR() __builtin_amdgcn_s_barrier()
#define LG0() asm volatile("s_waitcnt lgkmcnt(0)" ::: "memory")
#define TILE(T, P) do {                                                     \
    LOAD_A(0, P); LOAD_B(0, P);                                             \
    if ((T) + 1 < NT) STAGE_AU((T) + 1, 0, (P) ^ 1);                        \
    BAR(); LG0(); QUAD(0, 0); BAR();                                        \
    LOAD_B(1, P);                                                           \
    if ((T) + 1 < NT) STAGE_AU((T) + 1, 1, (P) ^ 1);                        \
    BAR(); LG0(); QUAD(0, 1); BAR();                                        \
    LOAD_A(1, P);                                                           \
    if ((T) + 2 < NT) STAGE_BU((T) + 2, 0, P);                              \
    BAR(); LG0(); QUAD(1, 1); BAR();                                        \
    if ((T) + 2 < NT) STAGE_BU((T) + 2, 1, P);                              \
    BAR(); QUAD(1, 0);                                                      \
    if ((T) + 2 < NT) {                                                     \
      asm volatile("s_waitcnt vmcnt(4)" ::: "memory");                      \
    } else if ((T) + 1 < NT) {                                              \
      asm volatile("s_waitcnt vmcnt(0)" ::: "memory");                      \
    }                                                                       \
    BAR();                                                                  \
  } while (0)

  STAGE_AU(0, 0, 0); STAGE_AU(0, 1, 0);
  STAGE_BU(0, 0, 0); STAGE_BU(0, 1, 0);
  STAGE_BU(1, 0, 1); STAGE_BU(1, 1, 1);
  asm volatile("s_waitcnt vmcnt(4)" ::: "memory");
  BAR();

  for (int T = 0; T < NT; T += 2) {
    TILE(T, 0);
    TILE(T + 1, 1);
  }
#undef TILE
#undef QUAD
#undef LOAD_A
#undef LOAD_B
#undef STAGE_AU
#undef STAGE_BU
#undef BAR

  // ---- full-line fp32 epilogue via per-wave 4KB scratch ----
  const int ocol0 = colBase + wc * 64 + lr;
  float bvv[4];
#pragma unroll
  for (int ni = 0; ni < 4; ++ni) bvv[ni] = bias[ocol0 + ni * 16];
  const int SB = 2 * BUFSZ + wid * 4096;
  const int orowB = rowBase + wr * WROWS;
  const int rd = lane >> 3;                  // 0..7
  const int bo = (lane & 7) * 16;            // 0..112
#pragma unroll
  for (int mi = 0; mi < M_REP; ++mi) {
#pragma unroll
    for (int ni = 0; ni < 4; ++ni) {
#pragma unroll
      for (int r = 0; r < 4; ++r) {
        int row16 = lg * 4 + r;
        int ad = SB + row16 * 256 +
                 (((ni * 16 + lr) * 4) ^ ((row16 & 7) << 4));
        *(float*)&lds[ad] = acc[mi][ni][r] + bvv[ni];
      }
    }
    asm volatile("s_waitcnt lgkmcnt(0)" ::: "memory");
    f32x4 v00 = *(const f32x4*)&lds[SB + rd * 256 + (bo ^ ((rd & 7) << 4))];
    f32x4 v01 = *(const f32x4*)&lds[SB + rd * 256 +
                                    ((bo + 128) ^ ((rd & 7) << 4))];
    f32x4 v10 = *(const f32x4*)&lds[SB + (rd + 8) * 256 +
                                    (bo ^ ((rd & 7) << 4))];
    f32x4 v11 = *(const f32x4*)&lds[SB + (rd + 8) * 256 +
                                    ((bo + 128) ^ ((rd & 7) << 4))];
    float* dst0 = Cout + (size_t)(orowB + mi * 16 + rd) * N +
                  colBase + wc * 64 + (lane & 7) * 4;
    *(f32x4*)dst0 = v00;
    *(f32x4*)(dst0 + 32) = v01;
    float* dst1 = dst0 + (size_t)8 * N;
    *(f32x4*)dst1 = v10;
    *(f32x4*)(dst1 + 32) = v11;
    asm volatile("s_waitcnt lgkmcnt(0)" ::: "memory");
  }
}

// ---------------- launch ----------------

extern "C" void kernel_launch(void* const* d_in, const int* in_sizes, int n_in,
                              void* d_out, int out_size, void* d_ws,
                              size_t ws_size, hipStream_t stream) {
  const float* x     = (const float*)d_in[0];
  const float* W1    = (const float*)d_in[1];
  const float* b1    = (const float*)d_in[2];
  const float* theta = (const float*)d_in[3];
  const float* qwr   = (const float*)d_in[4];
  const float* qwi   = (const float*)d_in[5];
  const float* W2    = (const float*)d_in[6];
  const float* b2    = (const float*)d_in[7];
  float* out = (float*)d_out;

  const int DF = 4096;
  size_t need = ((size_t)96 << 20) + DF * sizeof(float);
  if (ws_size < need) return;

  char* ws = (char*)d_ws;
  unsigned short* xb   = (unsigned short*)ws;                          // 16 MiB
  unsigned short* w1t  = (unsigned short*)(ws + ((size_t)16 << 20));   //  8 MiB
  unsigned short* w2t  = (unsigned short*)(ws + ((size_t)24 << 20));   //  8 MiB
  unsigned short* actb = (unsigned short*)(ws + ((size_t)32 << 20));   // 64 MiB
  float* c1 = (float*)(ws + ((size_t)96 << 20));

  prep<<<9232, 256, 0, stream>>>(x, W1, W2, theta, qwr, qwi,
                                 xb, w1t, w2t, c1);
  gemm1k<<<256, 512, 0, stream>>>(xb, w1t, b1, theta, c1, actb);
  gemm2k<<<256, 512, 0, stream>>>(actb, w2t, b2, out);
}

// Round 13
// 152.847 us; speedup vs baseline: 1.2295x; 1.0120x over previous
//
#include <hip/hip_runtime.h>

typedef __bf16 bf16x8 __attribute__((ext_vector_type(8)));
typedef short  s16x8  __attribute__((ext_vector_type(8)));
typedef float  f32x4  __attribute__((ext_vector_type(4)));

#define DEVINL __device__ __forceinline__

DEVINL unsigned short f2bf(float f) {
  unsigned int u = __builtin_bit_cast(unsigned int, f);
  u += 0x7fffu + ((u >> 16) & 1u);   // round-to-nearest-even
  return (unsigned short)(u >> 16);
}

DEVINL void async16(const void* g, void* l) {
  __builtin_amdgcn_global_load_lds(
      (const __attribute__((address_space(1))) unsigned int*)g,
      (__attribute__((address_space(3))) unsigned int*)l, 16, 0, 0);
}

// ---------------- fused prep kernel ----------------
// blocks [0,1024)    : x fp32 -> bf16 (grid-stride float4)
// blocks [1024,5120) : W1 [1024][4096] -> w1t [4096][1024] bf16
// blocks [5120,9216) : W2 [4096][1024] -> w2t [1024][4096] bf16
// blocks [9216,9232) : qconst

__global__ __launch_bounds__(256) void prep(
    const float* __restrict__ x, const float* __restrict__ W1,
    const float* __restrict__ W2, const float* __restrict__ theta,
    const float* __restrict__ wre, const float* __restrict__ wim,
    unsigned short* __restrict__ xb, unsigned short* __restrict__ w1t,
    unsigned short* __restrict__ w2t, float* __restrict__ c1) {
  __shared__ unsigned short tile[32][33];
  const int b = blockIdx.x;
  const int tid = threadIdx.x;
  if (b < 1024) {
    int i = b * 256 + tid;
#pragma unroll
    for (int k = 0; k < 8; ++k, i += 262144) {
      float4 v = ((const float4*)x)[i];
      ushort4 o;
      o.x = f2bf(v.x); o.y = f2bf(v.y); o.z = f2bf(v.z); o.w = f2bf(v.w);
      ((ushort4*)xb)[i] = o;
    }
  } else if (b < 5120) {
    int bb = b - 1024;                      // W1: R=1024, C=4096
    int bc = (bb & 127) * 32, br = (bb >> 7) * 32;
    int tx = tid & 31, ty = tid >> 5;
#pragma unroll
    for (int i = 0; i < 32; i += 8)
      tile[ty + i][tx] = f2bf(W1[(size_t)(br + ty + i) * 4096 + (bc + tx)]);
    __syncthreads();
#pragma unroll
    for (int i = 0; i < 32; i += 8)
      w1t[(size_t)(bc + ty + i) * 1024 + (br + tx)] = tile[tx][ty + i];
  } else if (b < 9216) {
    int bb = b - 5120;                      // W2: R=4096, C=1024
    int bc = (bb & 31) * 32, br = (bb >> 5) * 32;
    int tx = tid & 31, ty = tid >> 5;
#pragma unroll
    for (int i = 0; i < 32; i += 8)
      tile[ty + i][tx] = f2bf(W2[(size_t)(br + ty + i) * 1024 + (bc + tx)]);
    __syncthreads();
#pragma unroll
    for (int i = 0; i < 32; i += 8)
      w2t[(size_t)(bc + ty + i) * 4096 + (br + tx)] = tile[tx][ty + i];
  } else {
    int i = (b - 9216) * 256 + tid;         // qconst, n = 4096
    float t = theta[i];
    c1[i] = (cosf(t) * wre[i] + sinf(t) * wim[i]) * wim[i] * 0.1f;
  }
}

// ================= GEMM1: actb = relu(qt(xb @ w1t^T + b1)) =================
// 256x256 tile, BK=64, NT=16, REPS=2. R13: 2-barrier-per-K-tile window
// schedule (R4-verified hazard ledger) replacing the 8-barrier phase loop —
// GEMM1 was sync-bound (nothing saturated: MFMA 42%, LDS 48%, VALU 24%).
// Window WIN(T,P):
//  half1: read A0,B0(T); stage A(T+1)->P^1; Q(0,0); read B1(T); Q(0,1);
//         lgkm0; BAR   [all B-reads of T drained before any half2 stage]
//  half2: read A1(T); stage B(T+2)->P; Q(1,0); Q(1,1); lgkm0; vmcnt(4); BAR
// vmcnt ledger (steady state, at the vmcnt point): FIFO = [A(T+1)x4 (half1),
//  B(T+2)x4 (half2)]; vmcnt(4) -> A(T+1) landed. B(T+1) was certified by
//  WIN(T-1)'s vmcnt(4) (it was older than A(T) in that FIFO). Tail:
//  T==NT-2 -> vmcnt(0); T==NT-1 -> none. WAR: A(P^1) last read in
//  WIN(T-1) half2, drained by its lgkm0 before its BAR; stage after BAR.
// Rep boundary: stage next-rep tile0(A+B)+tile1(B) (12 loads) BEFORE the
//  epilogue; after epilogue vmcnt(16) drains exactly those 12 (FIFO =
//  [12 loads, 16 epilogue stores]); BAR; next rep.

__global__ __launch_bounds__(512, 1) void gemm1k(
    const unsigned short* __restrict__ A,    // xb  [8192][1024]
    const unsigned short* __restrict__ Bt,   // w1t [4096][1024]
    const float* __restrict__ bias,
    const float* __restrict__ theta,
    const float* __restrict__ c1,
    unsigned short* __restrict__ Cout) {     // actb [8192][4096]
  constexpr int K = 1024, N = 4096, NT = 16, REPS = 2;
  constexpr int WROWS = 128, M_REP = 8, MH = 4;
  constexpr int ABYTES = 32768, AH = 16384, AL = 2;
  constexpr int BUFSZ = 65536;
  constexpr int nTilesN = 8;                 // 4096 / 512

  __shared__ __align__(16) char lds[2 * BUFSZ + 16384];

  int nwg = gridDim.x;
  int wg = blockIdx.x;
  int sw = (wg & 7) * (nwg >> 3) + (wg >> 3);
  int rowBase = (sw / nTilesN) * 256;
  int colBase = (sw % nTilesN) * 512;

  const int t = threadIdx.x;
  const int lane = t & 63;
  const int wid = t >> 6;
  const int wr = wid >> 2, wc = wid & 3;
  const int lr = lane & 15;
  const int lg = lane >> 4;
  const int r7 = lane & 7;

  const int srow = t >> 3;
  const int scolB = ((t & 7) * 16) ^ ((srow & 7) << 4);
  const unsigned short* aSrcB = A  + (size_t)(rowBase + srow) * K + (scolB >> 1);
  const unsigned short* bSrcB = Bt + (size_t)(colBase + srow) * K + (scolB >> 1);

  const int aRd = (wr * WROWS + lr) * 128 + ((lg ^ r7) << 4);
  const int bRd = ABYTES + (wc * 64 + lr) * 128 + ((lg ^ r7) << 4);

#define STAGE_AU(S, U, P) do {                                              \
    _Pragma("unroll") for (int j = 0; j < AL; ++j)                          \
      async16(aSrcB + ((size_t)((U) * WROWS + j * 64) * K + (size_t)(S) * 64),\
              &lds[(P) * BUFSZ + (U) * AH + j * 8192 + t * 16]);            \
  } while (0)
#define STAGE_BU(SRC, S, U, P) do {                                         \
    _Pragma("unroll") for (int j = 0; j < 2; ++j)                           \
      async16((SRC) + ((size_t)((U) * 128 + j * 64) * K + (size_t)(S) * 64),\
              &lds[(P) * BUFSZ + ABYTES + (U) * 16384 + j * 8192 + t * 16]);\
  } while (0)
#define LOAD_A(MHh, P)                                                      \
  _Pragma("unroll") for (int mi = 0; mi < MH; ++mi)                         \
  _Pragma("unroll") for (int ks = 0; ks < 2; ++ks)                          \
    a[mi][ks] = __builtin_bit_cast(bf16x8, *(const s16x8*)&lds[             \
        (P) * BUFSZ + ((aRd + ((MHh) * MH + mi) * 2048) ^ (ks << 6))])
#define LOAD_B(NHh, P)                                                      \
  _Pragma("unroll") for (int nn = 0; nn < 2; ++nn)                          \
  _Pragma("unroll") for (int ks = 0; ks < 2; ++ks)                          \
    b[(NHh) * 2 + nn][ks] = __builtin_bit_cast(bf16x8, *(const s16x8*)&lds[ \
        (P) * BUFSZ + ((bRd + ((NHh) * 2 + nn) * 2048) ^ (ks << 6))])
#define QUAD(MHh, NHh)                                                      \
  __builtin_amdgcn_s_setprio(1);                                            \
  _Pragma("unroll") for (int mi = 0; mi < MH; ++mi)                         \
  _Pragma("unroll") for (int nn = 0; nn < 2; ++nn)                          \
  _Pragma("unroll") for (int ks = 0; ks < 2; ++ks)                          \
    acc[(MHh) * MH + mi][(NHh) * 2 + nn] =                                  \
        __builtin_amdgcn_mfma_f32_16x16x32_bf16(                            \
            a[mi][ks], b[(NHh) * 2 + nn][ks],                               \
            acc[(MHh) * MH + mi][(NHh) * 2 + nn], 0, 0, 0);                 \
  __builtin_amdgcn_s_setprio(0)
#define BAR() __builtin_amdgcn_s_barrier()
#define LG0() asm volatile("s_waitcnt lgkmcnt(0)" ::: "memory")
#define WIN(T, P) do {                                                      \
    /* half 1 */                                                            \
    LOAD_A(0, P); LOAD_B(0, P);                                             \
    if ((T) + 1 < NT) {                                                     \
      STAGE_AU((T) + 1, 0, (P) ^ 1);                                        \
      STAGE_AU((T) + 1, 1, (P) ^ 1);                                        \
    }                                                                       \
    QUAD(0, 0);                                                             \
    LOAD_B(1, P);                                                           \
    QUAD(0, 1);                                                             \
    LG0(); BAR();                                                           \
    /* half 2 */                                                            \
    LOAD_A(1, P);                                                           \
    if ((T) + 2 < NT) {                                                     \
      STAGE_BU(bSrcR, (T) + 2, 0, P);                                       \
      STAGE_BU(bSrcR, (T) + 2, 1, P);                                       \
    }                                                                       \
    QUAD(1, 0);                                                             \
    QUAD(1, 1);                                                             \
    LG0();                                                                  \
    if ((T) < NT - 2) {                                                     \
      asm volatile("s_waitcnt vmcnt(4)" ::: "memory");                      \
    } else if ((T) == NT - 2) {                                             \
      asm volatile("s_waitcnt vmcnt(0)" ::: "memory");                      \
    }                                                                       \
    BAR();                                                                  \
  } while (0)

  // prologue: tile0 A+B, tile1 B; drain tile0 (tile1 B may fly)
  STAGE_AU(0, 0, 0); STAGE_AU(0, 1, 0);
  STAGE_BU(bSrcB, 0, 0, 0); STAGE_BU(bSrcB, 0, 1, 0);
  STAGE_BU(bSrcB, 1, 0, 1); STAGE_BU(bSrcB, 1, 1, 1);
  asm volatile("s_waitcnt vmcnt(4)" ::: "memory");
  BAR();

  for (int rep = 0; rep < REPS; ++rep) {
    const unsigned short* bSrcR = bSrcB + (size_t)rep * 256 * K;
    f32x4 acc[M_REP][4] = {};
    bf16x8 a[MH][2], b[4][2];

    for (int T = 0; T < NT; T += 2) {
      WIN(T, 0);
      WIN(T + 1, 1);
    }

    // boundary staging for next rep (latency hides under epilogue)
    if (rep + 1 < REPS) {
      const unsigned short* bSrcN = bSrcB + (size_t)(rep + 1) * 256 * K;
      STAGE_AU(0, 0, 0); STAGE_AU(0, 1, 0);
      STAGE_BU(bSrcN, 0, 0, 0); STAGE_BU(bSrcN, 0, 1, 0);
      STAGE_BU(bSrcN, 1, 0, 1); STAGE_BU(bSrcN, 1, 1, 1);
    }

    // ---- fused epilogue (bias + quantum + relu), full-line bf16 stores ----
    const int colR = colBase + rep * 256;
    const int ocol0 = colR + wc * 64 + lr;
    float bvv[4], thv[4], ccv[4];
#pragma unroll
    for (int ni = 0; ni < 4; ++ni) {
      int n = ocol0 + ni * 16;
      bvv[ni] = bias[n]; thv[ni] = theta[n]; ccv[ni] = c1[n];
    }
    const int SB = 2 * BUFSZ + wid * 2048;
    const size_t growB = (size_t)(rowBase + wr * WROWS) * N;
    const int rd = lane >> 3;                // 0..7
    const int bo = (lane & 7) * 16;          // 0..112
#pragma unroll
    for (int mi = 0; mi < M_REP; ++mi) {
#pragma unroll
      for (int ni = 0; ni < 4; ++ni) {
#pragma unroll
        for (int r = 0; r < 4; ++r) {
          int row16 = lg * 4 + r;
          float h = acc[mi][ni][r] + bvv[ni];
          float q = h + ccv[ni] * __sinf(thv[ni] + 0.1f * h);
          unsigned short v = f2bf(fmaxf(q, 0.f));
          int ad = SB + row16 * 128 +
                   (((ni * 16 + lr) * 2) ^ ((row16 & 7) << 4));
          *(unsigned short*)&lds[ad] = v;
        }
      }
      s16x8 w0 = *(const s16x8*)&lds[SB + rd * 128 + (bo ^ ((rd & 7) << 4))];
      s16x8 w1 = *(const s16x8*)&lds[SB + (rd + 8) * 128 +
                                     (bo ^ ((rd & 7) << 4))];
      unsigned short* dst = Cout + growB + (size_t)(mi * 16 + rd) * N +
                            colR + wc * 64 + (lane & 7) * 8;
      *(s16x8*)dst = w0;
      *(s16x8*)(dst + (size_t)8 * N) = w1;   // rows rd and rd+8
    }

    if (rep + 1 < REPS) {
      // FIFO: [12 boundary loads, 16 epilogue stores] -> drain loads only
      asm volatile("s_waitcnt vmcnt(16)" ::: "memory");
      BAR();
    }
  }
#undef WIN
#undef QUAD
#undef LOAD_A
#undef LOAD_B
#undef STAGE_AU
#undef STAGE_BU
#undef BAR
#undef LG0
}

// ================= GEMM2: out = actb @ w2t^T + b2 (fp32) =================
// 128x256 tile, BK=64, NT=64 — unchanged from R10/R12 (at its LDS-read
// bound: 2136 cy/tile ~= 1536 read + 375 stage-write + barrier overhead).

__global__ __launch_bounds__(512, 1) void gemm2k(
    const unsigned short* __restrict__ A,    // actb [8192][4096]
    const unsigned short* __restrict__ Bt,   // w2t  [1024][4096]
    const float* __restrict__ bias,
    float* __restrict__ Cout) {              // out [8192][1024]
  constexpr int K = 4096, N = 1024, NT = 64;
  constexpr int WROWS = 64, M_REP = 4, MH = 2;
  constexpr int ABYTES = 16384, AH = 8192, AL = 1;
  constexpr int BUFSZ = 49152;
  constexpr int nTilesN = 4;

  __shared__ __align__(16) char lds[2 * BUFSZ + 32768];

  int nwg = gridDim.x;
  int wg = blockIdx.x;
  int sw = (wg & 7) * (nwg >> 3) + (wg >> 3);
  int rowBase = (sw / nTilesN) * 128;
  int colBase = (sw % nTilesN) * 256;

  const int t = threadIdx.x;
  const int lane = t & 63;
  const int wid = t >> 6;
  const int wr = wid >> 2, wc = wid & 3;
  const int lr = lane & 15;
  const int lg = lane >> 4;
  const int r7 = lane & 7;

  const int srow = t >> 3;
  const int scolB = ((t & 7) * 16) ^ ((srow & 7) << 4);
  const unsigned short* aSrcB = A  + (size_t)(rowBase + srow) * K + (scolB >> 1);
  const unsigned short* bSrcB = Bt + (size_t)(colBase + srow) * K + (scolB >> 1);

  const int aRd = (wr * WROWS + lr) * 128 + ((lg ^ r7) << 4);
  const int bRd = ABYTES + (wc * 64 + lr) * 128 + ((lg ^ r7) << 4);

  f32x4 acc[M_REP][4] = {};
  bf16x8 a[MH][2], b[4][2];

#define STAGE_AU(S, U, P)                                                   \
  async16(aSrcB + ((size_t)((U) * 64) * K + (size_t)(S) * 64),              \
          &lds[(P) * BUFSZ + (U) * AH + t * 16])
#define STAGE_BU(S, U, P) do {                                              \
    _Pragma("unroll") for (int j = 0; j < 2; ++j)                           \
      async16(bSrcB + ((size_t)((U) * 128 + j * 64) * K + (size_t)(S) * 64),\
              &lds[(P) * BUFSZ + ABYTES + (U) * 16384 + j * 8192 + t * 16]);\
  } while (0)
#define LOAD_A(MHh, P)                                                      \
  _Pragma("unroll") for (int mi = 0; mi < MH; ++mi)                         \
  _Pragma("unroll") for (int ks = 0; ks < 2; ++ks)                          \
    a[mi][ks] = __builtin_bit_cast(bf16x8, *(const s16x8*)&lds[             \
        (P) * BUFSZ + ((aRd + ((MHh) * MH + mi) * 2048) ^ (ks << 6))])
#define LOAD_B(NHh, P)                                                      \
  _Pragma("unroll") for (int nn = 0; nn < 2; ++nn)                          \
  _Pragma("unroll") for (int ks = 0; ks < 2; ++ks)                          \
    b[(NHh) * 2 + nn][ks] = __builtin_bit_cast(bf16x8, *(const s16x8*)&lds[ \
        (P) * BUFSZ + ((bRd + ((NHh) * 2 + nn) * 2048) ^ (ks << 6))])
#define QUAD(MHh, NHh)                                                      \
  __builtin_amdgcn_s_setprio(1);                                            \
  _Pragma("unroll") for (int mi = 0; mi < MH; ++mi)                         \
  _Pragma("unroll") for (int nn = 0; nn < 2; ++nn)                          \
  _Pragma("unroll") for (int ks = 0; ks < 2; ++ks)                          \
    acc[(MHh) * MH + mi][(NHh) * 2 + nn] =                                  \
        __builtin_amdgcn_mfma_f32_16x16x32_bf16(                            \
            a[mi][ks], b[(NHh) * 2 + nn][ks],                               \
            acc[(MHh) * MH + mi][(NHh) * 2 + nn], 0, 0, 0);                 \
  __builtin_amdgcn_s_setprio(0)
#define BAR() __builtin_amdgcn_s_barrier()
#define LG0() asm volatile("s_waitcnt lgkmcnt(0)" ::: "memory")
#define TILE(T, P) do {                                                     \
    LOAD_A(0, P); LOAD_B(0, P);                                             \
    if ((T) + 1 < NT) STAGE_AU((T) + 1, 0, (P) ^ 1);                        \
    BAR(); LG0(); QUAD(0, 0); BAR();                                        \
    LOAD_B(1, P);                                                           \
    if ((T) + 1 < NT) STAGE_AU((T) + 1, 1, (P) ^ 1);                        \
    BAR(); LG0(); QUAD(0, 1); BAR();                                        \
    LOAD_A(1, P);                                                           \
    if ((T) + 2 < NT) STAGE_BU((T) + 2, 0, P);                              \
    BAR(); LG0(); QUAD(1, 1); BAR();                                        \
    if ((T) + 2 < NT) STAGE_BU((T) + 2, 1, P);                              \
    BAR(); QUAD(1, 0);                                                      \
    if ((T) + 2 < NT) {                                                     \
      asm volatile("s_waitcnt vmcnt(4)" ::: "memory");                      \
    } else if ((T) + 1 < NT) {                                              \
      asm volatile("s_waitcnt vmcnt(0)" ::: "memory");                      \
    }                                                                       \
    BAR();                                                                  \
  } while (0)

  STAGE_AU(0, 0, 0); STAGE_AU(0, 1, 0);
  STAGE_BU(0, 0, 0); STAGE_BU(0, 1, 0);
  STAGE_BU(1, 0, 1); STAGE_BU(1, 1, 1);
  asm volatile("s_waitcnt vmcnt(4)" ::: "memory");
  BAR();

  for (int T = 0; T < NT; T += 2) {
    TILE(T, 0);
    TILE(T + 1, 1);
  }
#undef TILE
#undef QUAD
#undef LOAD_A
#undef LOAD_B
#undef STAGE_AU
#undef STAGE_BU
#undef BAR

  // ---- full-line fp32 epilogue via per-wave 4KB scratch ----
  const int ocol0 = colBase + wc * 64 + lr;
  float bvv[4];
#pragma unroll
  for (int ni = 0; ni < 4; ++ni) bvv[ni] = bias[ocol0 + ni * 16];
  const int SB = 2 * BUFSZ + wid * 4096;
  const int orowB = rowBase + wr * WROWS;
  const int rd = lane >> 3;                  // 0..7
  const int bo = (lane & 7) * 16;            // 0..112
#pragma unroll
  for (int mi = 0; mi < M_REP; ++mi) {
#pragma unroll
    for (int ni = 0; ni < 4; ++ni) {
#pragma unroll
      for (int r = 0; r < 4; ++r) {
        int row16 = lg * 4 + r;
        int ad = SB + row16 * 256 +
                 (((ni * 16 + lr) * 4) ^ ((row16 & 7) << 4));
        *(float*)&lds[ad] = acc[mi][ni][r] + bvv[ni];
      }
    }
    asm volatile("s_waitcnt lgkmcnt(0)" ::: "memory");
    f32x4 v00 = *(const f32x4*)&lds[SB + rd * 256 + (bo ^ ((rd & 7) << 4))];
    f32x4 v01 = *(const f32x4*)&lds[SB + rd * 256 +
                                    ((bo + 128) ^ ((rd & 7) << 4))];
    f32x4 v10 = *(const f32x4*)&lds[SB + (rd + 8) * 256 +
                                    (bo ^ ((rd & 7) << 4))];
    f32x4 v11 = *(const f32x4*)&lds[SB + (rd + 8) * 256 +
                                    ((bo + 128) ^ ((rd & 7) << 4))];
    float* dst0 = Cout + (size_t)(orowB + mi * 16 + rd) * N +
                  colBase + wc * 64 + (lane & 7) * 4;
    *(f32x4*)dst0 = v00;
    *(f32x4*)(dst0 + 32) = v01;
    float* dst1 = dst0 + (size_t)8 * N;
    *(f32x4*)dst1 = v10;
    *(f32x4*)(dst1 + 32) = v11;
    asm volatile("s_waitcnt lgkmcnt(0)" ::: "memory");
  }
}

// ---------------- launch ----------------

extern "C" void kernel_launch(void* const* d_in, const int* in_sizes, int n_in,
                              void* d_out, int out_size, void* d_ws,
                              size_t ws_size, hipStream_t stream) {
  const float* x     = (const float*)d_in[0];
  const float* W1    = (const float*)d_in[1];
  const float* b1    = (const float*)d_in[2];
  const float* theta = (const float*)d_in[3];
  const float* qwr   = (const float*)d_in[4];
  const float* qwi   = (const float*)d_in[5];
  const float* W2    = (const float*)d_in[6];
  const float* b2    = (const float*)d_in[7];
  float* out = (float*)d_out;

  const int DF = 4096;
  size_t need = ((size_t)96 << 20) + DF * sizeof(float);
  if (ws_size < need) return;

  char* ws = (char*)d_ws;
  unsigned short* xb   = (unsigned short*)ws;                          // 16 MiB
  unsigned short* w1t  = (unsigned short*)(ws + ((size_t)16 << 20));   //  8 MiB
  unsigned short* w2t  = (unsigned short*)(ws + ((size_t)24 << 20));   //  8 MiB
  unsigned short* actb = (unsigned short*)(ws + ((size_t)32 << 20));   // 64 MiB
  float* c1 = (float*)(ws + ((size_t)96 << 20));

  prep<<<9232, 256, 0, stream>>>(x, W1, W2, theta, qwr, qwi,
                                 xb, w1t, w2t, c1);
  gemm1k<<<256, 512, 0, stream>>>(xb, w1t, b1, theta, c1, actb);
  gemm2k<<<256, 512, 0, stream>>>(actb, w2t, b2, out);
}